// Round 1
// baseline (14758.885 us; speedup 1.0000x reference)
//
#include <hip/hip_runtime.h>
#include <hip/hip_bf16.h>

// Problem constants
#define B_  256
#define S_  512
#define I_  512
#define H_  1024
#define G3_ 3072

typedef __bf16 bf16x8 __attribute__((ext_vector_type(8)));
typedef float  f32x4  __attribute__((ext_vector_type(4)));

union U16x8 { int4 i; bf16x8 b; unsigned short s[8]; };

__device__ __forceinline__ unsigned short f2bf(float f) {
    union { float f; unsigned u; } v; v.f = f;
    unsigned r = v.u + 0x7FFFu + ((v.u >> 16) & 1u);   // RNE
    return (unsigned short)(r >> 16);
}

__device__ __forceinline__ bf16x8 ldb(const unsigned short* p) {
    U16x8 u; u.i = *(const int4*)p; return u.b;
}

__device__ __forceinline__ bf16x8 packx(const float* p) {
    float4 a = *(const float4*)p;
    float4 c = *(const float4*)(p + 4);
    U16x8 u;
    u.s[0] = f2bf(a.x); u.s[1] = f2bf(a.y); u.s[2] = f2bf(a.z); u.s[3] = f2bf(a.w);
    u.s[4] = f2bf(c.x); u.s[5] = f2bf(c.y); u.s[6] = f2bf(c.z); u.s[7] = f2bf(c.w);
    return u.b;
}

// Convert weights fp32 -> bf16 once per call; zero h state.
__global__ void prep_kernel(const float* __restrict__ wh, const float* __restrict__ wi,
                            float* __restrict__ h32, unsigned short* __restrict__ hbA,
                            unsigned short* __restrict__ whb, unsigned short* __restrict__ wib) {
    int idx = blockIdx.x * blockDim.x + threadIdx.x;
    int stride = gridDim.x * blockDim.x;
    for (int i = idx; i < G3_ * H_; i += stride) whb[i] = f2bf(wh[i]);
    for (int i = idx; i < G3_ * I_; i += stride) wib[i] = f2bf(wi[i]);
    for (int i = idx; i < B_ * H_; i += stride) { h32[i] = 0.f; hbA[i] = 0; }
}

// One GRU timestep. Grid: 1024 blocks x 64 threads (1 wave).
// blockIdx: hblk = bid & 63 (16 hidden units), mt = bid >> 6 (16 batch rows).
// Each wave: M=16 (batch), N=48 (3 gate rows per hidden unit), K=1024 (wh) + 512 (wi),
// via 16x16x32 bf16 MFMA. acc_ia / acc_ha kept separate (n-gate needs r*(ha+bn)).
__global__ __launch_bounds__(64) void gru_step(
    const float* __restrict__ x,
    const unsigned short* __restrict__ whb,
    const unsigned short* __restrict__ wib,
    const float* __restrict__ bi,
    const float* __restrict__ bn,
    float* __restrict__ h32,
    const unsigned short* __restrict__ hin,
    unsigned short* __restrict__ hout,
    int t)
{
    const int bid  = blockIdx.x;
    const int hblk = bid & 63;
    const int mt   = bid >> 6;
    const int k0   = hblk << 4;      // hidden unit base
    const int b0   = mt << 4;        // batch row base
    const int lane = threadIdx.x & 63;
    const int col  = lane & 15;      // A: m index / B: n index
    const int quad = lane >> 4;      // k sub-block

    // A operand: h_prev (bf16) rows = batch, contiguous 8 bf16 per lane
    const unsigned short* ha_p = hin + (((size_t)(b0 + col)) << 10) + (quad << 3);
    // B operand: wh rows = gate rows {k, k+1024, k+2048}
    const unsigned short* br_p = whb + (((size_t)(k0 + col)) << 10) + (quad << 3);
    const unsigned short* bz_p = br_p + ((size_t)1 << 20);
    const unsigned short* ba_p = br_p + ((size_t)2 << 20);

    f32x4 acc_r  = {0.f, 0.f, 0.f, 0.f};
    f32x4 acc_z  = {0.f, 0.f, 0.f, 0.f};
    f32x4 acc_ia = {0.f, 0.f, 0.f, 0.f};
    f32x4 acc_ha = {0.f, 0.f, 0.f, 0.f};

    // h @ wh^T : K = 1024 = 32 mfma steps
    #pragma unroll 4
    for (int kk = 0; kk < 32; ++kk) {
        bf16x8 a = ldb(ha_p + kk * 32);
        acc_r  = __builtin_amdgcn_mfma_f32_16x16x32_bf16(a, ldb(br_p + kk * 32), acc_r,  0, 0, 0);
        acc_z  = __builtin_amdgcn_mfma_f32_16x16x32_bf16(a, ldb(bz_p + kk * 32), acc_z,  0, 0, 0);
        acc_ha = __builtin_amdgcn_mfma_f32_16x16x32_bf16(a, ldb(ba_p + kk * 32), acc_ha, 0, 0, 0);
    }

    // x_t @ wi^T : K = 512 = 16 mfma steps (x loaded fp32, cast to bf16)
    const float* x_p = x + ((((size_t)(b0 + col)) * S_ + (size_t)t) << 9) + (quad << 3);
    const unsigned short* cr_p = wib + (((size_t)(k0 + col)) << 9) + (quad << 3);
    const unsigned short* cz_p = cr_p + ((size_t)1 << 19);
    const unsigned short* ca_p = cr_p + ((size_t)2 << 19);

    #pragma unroll 4
    for (int kk = 0; kk < 16; ++kk) {
        bf16x8 a = packx(x_p + kk * 32);
        acc_r  = __builtin_amdgcn_mfma_f32_16x16x32_bf16(a, ldb(cr_p + kk * 32), acc_r,  0, 0, 0);
        acc_z  = __builtin_amdgcn_mfma_f32_16x16x32_bf16(a, ldb(cz_p + kk * 32), acc_z,  0, 0, 0);
        acc_ia = __builtin_amdgcn_mfma_f32_16x16x32_bf16(a, ldb(ca_p + kk * 32), acc_ia, 0, 0, 0);
    }

    // Epilogue: C/D layout col = lane&15 (hidden unit), row = quad*4 + reg (batch)
    const int hcol = k0 + col;
    const float bir = bi[hcol];
    const float biz = bi[H_ + hcol];
    const float bia = bi[2 * H_ + hcol];
    const float bnv = bn[hcol];

    #pragma unroll
    for (int r_ = 0; r_ < 4; ++r_) {
        const int brow = b0 + (quad << 2) + r_;
        const size_t off = (((size_t)brow) << 10) + hcol;
        float rg = 1.f / (1.f + __expf(-(acc_r[r_] + bir)));
        float zg = 1.f / (1.f + __expf(-(acc_z[r_] + biz)));
        float pa = acc_ia[r_] + bia + rg * (acc_ha[r_] + bnv);
        float e2 = __expf(2.f * pa);
        float ng = 1.f - 2.f / (e2 + 1.f);   // tanh(pa)
        float hold = h32[off];
        float hnew = ng + zg * (hold - ng);
        h32[off]  = hnew;
        hout[off] = f2bf(hnew);
    }
}

// energies[b] = h_T[b] . wl + bl
__global__ __launch_bounds__(256) void final_kernel(const float* __restrict__ h32,
                                                    const float* __restrict__ wl,
                                                    const float* __restrict__ bl,
                                                    float* __restrict__ out) {
    const int b = blockIdx.x;
    float s = 0.f;
    for (int k = threadIdx.x; k < H_; k += 256)
        s += h32[((size_t)b << 10) + k] * wl[k];
    #pragma unroll
    for (int off = 32; off > 0; off >>= 1)
        s += __shfl_down(s, off, 64);
    __shared__ float red[4];
    const int wave = threadIdx.x >> 6;
    const int lane = threadIdx.x & 63;
    if (lane == 0) red[wave] = s;
    __syncthreads();
    if (threadIdx.x == 0)
        out[b] = red[0] + red[1] + red[2] + red[3] + bl[0];
}

extern "C" void kernel_launch(void* const* d_in, const int* in_sizes, int n_in,
                              void* d_out, int out_size, void* d_ws, size_t ws_size,
                              hipStream_t stream) {
    const float* x  = (const float*)d_in[0];
    const float* wi = (const float*)d_in[1];
    const float* wh = (const float*)d_in[2];
    const float* bi = (const float*)d_in[3];
    const float* bn = (const float*)d_in[4];
    const float* wl = (const float*)d_in[5];
    const float* bl = (const float*)d_in[6];
    float* out = (float*)d_out;

    // Workspace layout (needs ~11 MB):
    // [0, 1MB)      h32  fp32 (256x1024)
    // [1MB, 1.5MB)  hbA  bf16 (256x1024)
    // [1.5MB, 2MB)  hbB  bf16 (256x1024)
    // [2MB, 8MB)    whb  bf16 (3072x1024)
    // [8MB, 11MB)   wib  bf16 (3072x512)
    char* ws = (char*)d_ws;
    float*          h32 = (float*)ws;
    unsigned short* hbA = (unsigned short*)(ws + (1u << 20));
    unsigned short* hbB = (unsigned short*)(ws + (1u << 20) + (512u << 10));
    unsigned short* whb = (unsigned short*)(ws + (2u << 20));
    unsigned short* wib = (unsigned short*)(ws + (8u << 20));

    prep_kernel<<<1024, 256, 0, stream>>>(wh, wi, h32, hbA, whb, wib);

    for (int t = 0; t < S_; ++t) {
        const unsigned short* hin = (t & 1) ? hbB : hbA;
        unsigned short*      hout = (t & 1) ? hbA : hbB;
        gru_step<<<1024, 64, 0, stream>>>(x, whb, wib, bi, bn, h32, hin, hout, t);
    }

    final_kernel<<<B_, 256, 0, stream>>>(h32, wl, bl, out);
}

// Round 2
// 11558.877 us; speedup vs baseline: 1.2768x; 1.2768x over previous
//
#include <hip/hip_runtime.h>
#include <hip/hip_bf16.h>

// Problem: GRU scan B=256, S=512, I=512, H=1024 + Linear(H,1).
// R2 design: persistent-weight kernel.
//   - 256 blocks x 256 threads (4 waves). Block (mt, hblk) owns 16 hidden units
//     (gate triple) x 64 batch rows. Waves split K: wave w holds wh k in
//     [w*256,w*256+256) and wi k in [w*128,w*128+128) as MFMA B-fragments in
//     VGPRs (36 frags = 144 VGPRs) -- weights are fetched from global EXACTLY
//     ONCE for the whole scan (vs once per step in R1 = ~144 MB/step).
//   - Per step: x-phase MFMAs (no dependency, runs before barrier), spin-wait
//     on per-mt-group generation counter, h-phase MFMAs, LDS partial-sum
//     reduction across the 4 K-split waves, fused gate epilogue, bf16 h store
//     to ping-pong buffer, arrive.
//   - Cross-XCD h visibility: relaxed spin + one agent acquire fence per step;
//     release fence + relaxed fetch_add on arrive. fp32 h master kept in LDS
//     (block-exclusive) for accuracy; bf16 h only feeds MFMA.
//   - Residency: 1 block/CU (LDS 56.6 KB, ~280 VGPR/wave), grid = 256 = #CUs,
//     so all blocks are co-resident; spin barrier is safe.

#define B_  256
#define S_  512
#define I_  512
#define H_  1024
#define GSIZE 64   // blocks per mt-group (64 hblk)

typedef __bf16 bf16x8 __attribute__((ext_vector_type(8)));
typedef float  f32x4  __attribute__((ext_vector_type(4)));

union U16x8 { int4 i; bf16x8 b; unsigned short s[8]; unsigned u[4]; };

// pack two fp32 -> packed bf16 pair (round-half-up; tie-bias ~2^-17 ulp, negligible)
__device__ __forceinline__ unsigned pack2bf(float lo, float hi) {
    union { float f; unsigned u; } a, b;
    a.f = lo; b.f = hi;
    return __builtin_amdgcn_perm(b.u + 0x8000u, a.u + 0x8000u, 0x07060302u);
}
__device__ __forceinline__ unsigned short f2bf1(float f) {
    union { float f; unsigned u; } v; v.f = f;
    return (unsigned short)((v.u + 0x8000u) >> 16);
}
__device__ __forceinline__ bf16x8 ldb(const unsigned short* p) {
    U16x8 u; u.i = *(const int4*)p; return u.b;
}

// -------- prep: fp32->bf16 weight convert, zero h0 + barrier words --------
__global__ void prep_kernel(const float* __restrict__ wh, const float* __restrict__ wi,
                            unsigned* __restrict__ hbA_u, unsigned* __restrict__ whb_u,
                            unsigned* __restrict__ wib_u, unsigned* __restrict__ bar) {
    int idx = blockIdx.x * blockDim.x + threadIdx.x;
    int stride = gridDim.x * blockDim.x;
    const float2* wh2 = (const float2*)wh;
    const float2* wi2 = (const float2*)wi;
    for (int i = idx; i < 3 * H_ * H_ / 2; i += stride) { float2 v = wh2[i]; whb_u[i] = pack2bf(v.x, v.y); }
    for (int i = idx; i < 3 * H_ * I_ / 2; i += stride) { float2 v = wi2[i]; wib_u[i] = pack2bf(v.x, v.y); }
    for (int i = idx; i < B_ * H_ / 2; i += stride) hbA_u[i] = 0u;
    if (idx < 8) bar[idx] = 0u;
}

// -------- persistent GRU scan --------
__global__ __launch_bounds__(256, 1) void gru_persistent(
    const float* __restrict__ x,
    const unsigned short* __restrict__ whb,
    const unsigned short* __restrict__ wib,
    const float* __restrict__ bi,
    const float* __restrict__ bn,
    unsigned short* __restrict__ hbufA,
    unsigned short* __restrict__ hbufB,
    float* __restrict__ h32g,
    unsigned* __restrict__ bar)     // bar[0..3]=ctr per mt, bar[4..7]=gen per mt
{
    // partial[writer p][slot 0..2][m-sub 16][n 68 pad (64 used: 4 groups x 16 hid)]
    __shared__ float partial[4 * 3 * 16 * 68];
    __shared__ float h32s[64 * 17];   // fp32 h master, block-exclusive, padded

    const int tid  = threadIdx.x;
    const int w    = tid >> 6;        // wave 0..3 (K-split)
    const int lane = tid & 63;
    const int col  = lane & 15;
    const int quad = lane >> 4;

    const int hblk = blockIdx.x & 63;
    const int mt   = blockIdx.x >> 6;
    const int k0   = hblk << 4;       // hidden base
    const int b0   = mt << 6;         // batch base (64 rows)
    const int kwh  = w << 8;          // wh k-offset
    const int kwi  = w << 7;          // wi k-offset

    // ---- persistent B fragments (loaded once) ----
    bf16x8 Bh[3][8];
    bf16x8 Bx[3][4];
    #pragma unroll
    for (int g = 0; g < 3; ++g) {
        const unsigned short* bh = whb + ((size_t)(g * H_ + k0 + col)) * H_ + kwh + (quad << 3);
        #pragma unroll
        for (int kk = 0; kk < 8; ++kk) Bh[g][kk] = ldb(bh + kk * 32);
        const unsigned short* bx = wib + ((size_t)(g * H_ + k0 + col)) * I_ + kwi + (quad << 3);
        #pragma unroll
        for (int kk = 0; kk < 4; ++kk) Bx[g][kk] = ldb(bx + kk * 32);
    }

    const int hcol = k0 + col;
    const float bir = bi[hcol], biz = bi[H_ + hcol], bia = bi[2 * H_ + hcol], bnv = bn[hcol];

    for (int i = tid; i < 64 * 17; i += 256) h32s[i] = 0.f;
    __syncthreads();

    unsigned* ctr = bar + mt;
    unsigned* gen = bar + 4 + mt;

    const f32x4 zero4 = {0.f, 0.f, 0.f, 0.f};

    for (int t = 0; t < S_; ++t) {
        f32x4 acc[4][4];   // [mi][0=r,1=z,2=ia,3=ha]
        #pragma unroll
        for (int mi = 0; mi < 4; ++mi)
            #pragma unroll
            for (int j = 0; j < 4; ++j) acc[mi][j] = zero4;

        // ---- x-phase (independent of h -> overlaps barrier skew) ----
        const float* xbase = x + ((size_t)(b0 + col) * S_ + (size_t)t) * I_ + kwi + (quad << 3);
        #pragma unroll
        for (int kk = 0; kk < 4; ++kk) {
            #pragma unroll
            for (int mi = 0; mi < 4; ++mi) {
                const float* p = xbase + (size_t)mi * 16 * S_ * I_ + kk * 32;
                float4 f0 = *(const float4*)p;
                float4 f1 = *(const float4*)(p + 4);
                U16x8 u;
                u.u[0] = pack2bf(f0.x, f0.y);
                u.u[1] = pack2bf(f0.z, f0.w);
                u.u[2] = pack2bf(f1.x, f1.y);
                u.u[3] = pack2bf(f1.z, f1.w);
                bf16x8 a = u.b;
                acc[mi][0] = __builtin_amdgcn_mfma_f32_16x16x32_bf16(a, Bx[0][kk], acc[mi][0], 0, 0, 0);
                acc[mi][1] = __builtin_amdgcn_mfma_f32_16x16x32_bf16(a, Bx[1][kk], acc[mi][1], 0, 0, 0);
                acc[mi][2] = __builtin_amdgcn_mfma_f32_16x16x32_bf16(a, Bx[2][kk], acc[mi][2], 0, 0, 0);
            }
        }

        // ---- wait for h(t) (all blocks of this mt-group done with step t-1) ----
        if (t > 0) {
            if (tid == 0) {
                while (__hip_atomic_load(gen, __ATOMIC_RELAXED, __HIP_MEMORY_SCOPE_AGENT) < (unsigned)t)
                    __builtin_amdgcn_s_sleep(2);
                __builtin_amdgcn_fence(__ATOMIC_ACQUIRE, "agent");  // one L1/L2 inv per step
            }
            __syncthreads();
        }

        // ---- h-phase ----
        const unsigned short* hcur = (t & 1) ? hbufB : hbufA;
        const unsigned short* hrow = hcur + (size_t)(b0 + col) * H_ + kwh + (quad << 3);
        #pragma unroll
        for (int kk = 0; kk < 8; ++kk) {
            #pragma unroll
            for (int mi = 0; mi < 4; ++mi) {
                bf16x8 a = ldb(hrow + (size_t)mi * 16 * H_ + kk * 32);
                acc[mi][0] = __builtin_amdgcn_mfma_f32_16x16x32_bf16(a, Bh[0][kk], acc[mi][0], 0, 0, 0);
                acc[mi][1] = __builtin_amdgcn_mfma_f32_16x16x32_bf16(a, Bh[1][kk], acc[mi][1], 0, 0, 0);
                acc[mi][3] = __builtin_amdgcn_mfma_f32_16x16x32_bf16(a, Bh[2][kk], acc[mi][3], 0, 0, 0);
            }
        }

        // ---- publish partials for the 3 m-slices this wave doesn't own ----
        #pragma unroll
        for (int mi = 0; mi < 4; ++mi) {
            if (mi == w) continue;                      // own slice stays in regs
            int slot = mi - (mi > w ? 1 : 0);
            float* dst = partial + (size_t)((w * 3 + slot) * 16) * 68;
            #pragma unroll
            for (int j = 0; j < 4; ++j)
                #pragma unroll
                for (int r = 0; r < 4; ++r)
                    dst[((quad << 2) + r) * 68 + j * 16 + col] = acc[mi][j][r];
        }
        __syncthreads();

        // ---- epilogue: wave w handles batch rows [w*16, w*16+16) ----
        unsigned short* hnext = (t & 1) ? hbufA : hbufB;
        #pragma unroll
        for (int r = 0; r < 4; ++r) {
            float sr = 0.f, sz = 0.f, sia = 0.f, sha = 0.f;
            #pragma unroll
            for (int mi = 0; mi < 4; ++mi)
                if (mi == w) { sr = acc[mi][0][r]; sz = acc[mi][1][r]; sia = acc[mi][2][r]; sha = acc[mi][3][r]; }
            #pragma unroll
            for (int p = 0; p < 4; ++p) {
                if (p == w) continue;
                int slot = w - (w > p ? 1 : 0);
                const float* src = partial + (size_t)(((p * 3 + slot) * 16 + (quad << 2) + r)) * 68 + col;
                sr  += src[0];
                sz  += src[16];
                sia += src[32];
                sha += src[48];
            }
            float rg = 1.f / (1.f + __expf(-(sr + bir)));
            float zg = 1.f / (1.f + __expf(-(sz + biz)));
            float pa = sia + bia + rg * (sha + bnv);
            float e2 = __expf(2.f * pa);
            float ng = 1.f - 2.f / (e2 + 1.f);
            int m = (w << 4) + (quad << 2) + r;         // local batch row 0..63
            float hold = h32s[m * 17 + col];
            float hnew = ng + zg * (hold - ng);
            h32s[m * 17 + col] = hnew;
            size_t off = (size_t)(b0 + m) * H_ + k0 + col;
            hnext[off] = f2bf1(hnew);
            if (t == S_ - 1) h32g[off] = hnew;
        }

        // ---- arrive ----
        __syncthreads();   // partial reads done; all waves' h stores vmcnt-drained
        if (tid == 0) {
            __builtin_amdgcn_fence(__ATOMIC_RELEASE, "agent");   // wbl2: h visible cross-XCD
            unsigned old = __hip_atomic_fetch_add(ctr, 1u, __ATOMIC_RELAXED, __HIP_MEMORY_SCOPE_AGENT);
            if (old == GSIZE - 1) {
                __hip_atomic_store(ctr, 0u, __ATOMIC_RELAXED, __HIP_MEMORY_SCOPE_AGENT);
                __hip_atomic_store(gen, (unsigned)(t + 1), __ATOMIC_RELEASE, __HIP_MEMORY_SCOPE_AGENT);
            }
        }
    }
}

// -------- final linear: energies[b] = h_T[b] . wl + bl --------
__global__ __launch_bounds__(256) void final_kernel(const float* __restrict__ h32,
                                                    const float* __restrict__ wl,
                                                    const float* __restrict__ bl,
                                                    float* __restrict__ out) {
    const int b = blockIdx.x;
    float s = 0.f;
    for (int k = threadIdx.x; k < H_; k += 256)
        s += h32[((size_t)b << 10) + k] * wl[k];
    #pragma unroll
    for (int off = 32; off > 0; off >>= 1)
        s += __shfl_down(s, off, 64);
    __shared__ float red[4];
    const int wave = threadIdx.x >> 6;
    const int lane = threadIdx.x & 63;
    if (lane == 0) red[wave] = s;
    __syncthreads();
    if (threadIdx.x == 0)
        out[b] = red[0] + red[1] + red[2] + red[3] + bl[0];
}

extern "C" void kernel_launch(void* const* d_in, const int* in_sizes, int n_in,
                              void* d_out, int out_size, void* d_ws, size_t ws_size,
                              hipStream_t stream) {
    const float* x  = (const float*)d_in[0];
    const float* wi = (const float*)d_in[1];
    const float* wh = (const float*)d_in[2];
    const float* bi = (const float*)d_in[3];
    const float* bn = (const float*)d_in[4];
    const float* wl = (const float*)d_in[5];
    const float* bl = (const float*)d_in[6];
    float* out = (float*)d_out;

    // Workspace layout (~11 MB + 32 B):
    // [0,1M)      h32g fp32 (256x1024)      [1M,1.5M)  hbA bf16
    // [1.5M,2M)   hbB bf16                  [2M,8M)    whb bf16 (3072x1024)
    // [8M,11M)    wib bf16 (3072x512)       [11M,+32)  barrier ctr[4]/gen[4]
    char* ws = (char*)d_ws;
    float*          h32g = (float*)ws;
    unsigned short* hbA  = (unsigned short*)(ws + (1u << 20));
    unsigned short* hbB  = (unsigned short*)(ws + (1u << 20) + (512u << 10));
    unsigned short* whb  = (unsigned short*)(ws + (2u << 20));
    unsigned short* wib  = (unsigned short*)(ws + (8u << 20));
    unsigned*       bar  = (unsigned*)(ws + (11u << 20));

    prep_kernel<<<1024, 256, 0, stream>>>(wh, wi, (unsigned*)hbA, (unsigned*)whb, (unsigned*)wib, bar);
    gru_persistent<<<256, 256, 0, stream>>>(x, whb, wib, bi, bn, hbA, hbB, h32g, bar);
    final_kernel<<<B_, 256, 0, stream>>>(h32g, wl, bl, out);
}

// Round 3
// 9318.164 us; speedup vs baseline: 1.5839x; 1.2405x over previous
//
#include <hip/hip_runtime.h>
#include <hip/hip_bf16.h>

// GRU scan B=256, S=512, I=512, H=1024 + Linear(H,1).
// R3: persistent-weight kernel with LIGHTWEIGHT cross-block sync.
//   R2 post-mortem: 22 us/step, MfmaUtil 4.3% -- barrier-bound. The agent
//   acquire/release fences (buffer_inv / buffer_wbl2) nuked L2 every step
//   (FETCH_SIZE showed x refetched 8x from HBM) and 64 serialized fetch-adds
//   per group dominated the critical path.
//   R3 changes:
//   - h ping-pong accessed ONLY via device-scope (sc1) relaxed atomics:
//     bypasses the non-coherent per-XCD L2 for h alone; x/weights stay L2-
//     cached. No fences anywhere in the loop.
//   - Barrier = per-block flag (64B padded). Producer: __syncthreads()
//     (compiler drains vmcnt(0) before s_barrier -> h stores are at the
//     coherence point) then tid0 stores flag=t+1 relaxed-agent. Consumer:
//     wave 0 lane i spins on flag of group-block i (64 parallel loads, no
//     RMW serialization), then __syncthreads releases the block.
//   - x-phase (no h dependency) still runs before the wait to absorb skew.

#define B_  256
#define S_  512
#define I_  512
#define H_  1024
#define GSIZE 64   // blocks per mt-group

typedef __bf16 bf16x8 __attribute__((ext_vector_type(8)));
typedef float  f32x4  __attribute__((ext_vector_type(4)));

union U16x8 { int4 i; bf16x8 b; unsigned short s[8]; unsigned u[4]; };

__device__ __forceinline__ unsigned pack2bf(float lo, float hi) {
    union { float f; unsigned u; } a, b;
    a.f = lo; b.f = hi;
    return __builtin_amdgcn_perm(b.u + 0x8000u, a.u + 0x8000u, 0x07060302u);
}
__device__ __forceinline__ unsigned short f2bf1(float f) {
    union { float f; unsigned u; } v; v.f = f;
    return (unsigned short)((v.u + 0x8000u) >> 16);
}
__device__ __forceinline__ bf16x8 ldb(const unsigned short* p) {
    U16x8 u; u.i = *(const int4*)p; return u.b;
}
// device-scope (sc1) 16B h load as two relaxed 8B atomic loads (pipelined,
// no per-load waitcnt since relaxed)
__device__ __forceinline__ bf16x8 ldh_dev(const unsigned long long* p) {
    unsigned long long lo = __hip_atomic_load(p,     __ATOMIC_RELAXED, __HIP_MEMORY_SCOPE_AGENT);
    unsigned long long hi = __hip_atomic_load(p + 1, __ATOMIC_RELAXED, __HIP_MEMORY_SCOPE_AGENT);
    union { unsigned long long q[2]; bf16x8 b; } u;
    u.q[0] = lo; u.q[1] = hi; return u.b;
}

// -------- prep: fp32->bf16 weight convert, zero h0 + flags --------
__global__ void prep_kernel(const float* __restrict__ wh, const float* __restrict__ wi,
                            unsigned* __restrict__ hbA_u, unsigned* __restrict__ whb_u,
                            unsigned* __restrict__ wib_u, unsigned* __restrict__ flags) {
    int idx = blockIdx.x * blockDim.x + threadIdx.x;
    int stride = gridDim.x * blockDim.x;
    const float2* wh2 = (const float2*)wh;
    const float2* wi2 = (const float2*)wi;
    for (int i = idx; i < 3 * H_ * H_ / 2; i += stride) { float2 v = wh2[i]; whb_u[i] = pack2bf(v.x, v.y); }
    for (int i = idx; i < 3 * H_ * I_ / 2; i += stride) { float2 v = wi2[i]; wib_u[i] = pack2bf(v.x, v.y); }
    for (int i = idx; i < B_ * H_ / 2; i += stride) hbA_u[i] = 0u;
    if (idx < 256 * 16) flags[idx] = 0u;   // 256 blocks x 64B-padded flag
}

// -------- persistent GRU scan --------
__global__ __launch_bounds__(256, 1) void gru_persistent(
    const float* __restrict__ x,
    const unsigned short* __restrict__ whb,
    const unsigned short* __restrict__ wib,
    const float* __restrict__ bi,
    const float* __restrict__ bn,
    unsigned short* __restrict__ hbufA,
    unsigned short* __restrict__ hbufB,
    float* __restrict__ h32g,
    unsigned* __restrict__ flags)   // flags[blk*16]: steps completed by blk
{
    __shared__ float partial[4 * 3 * 16 * 68];
    __shared__ float h32s[64 * 17];

    const int tid  = threadIdx.x;
    const int w    = tid >> 6;
    const int lane = tid & 63;
    const int col  = lane & 15;
    const int quad = lane >> 4;

    const int hblk = blockIdx.x & 63;
    const int mt   = blockIdx.x >> 6;
    const int k0   = hblk << 4;
    const int b0   = mt << 6;
    const int kwh  = w << 8;
    const int kwi  = w << 7;

    // ---- persistent B fragments (loaded once, normal cached loads) ----
    bf16x8 Bh[3][8];
    bf16x8 Bx[3][4];
    #pragma unroll
    for (int g = 0; g < 3; ++g) {
        const unsigned short* bh = whb + ((size_t)(g * H_ + k0 + col)) * H_ + kwh + (quad << 3);
        #pragma unroll
        for (int kk = 0; kk < 8; ++kk) Bh[g][kk] = ldb(bh + kk * 32);
        const unsigned short* bx = wib + ((size_t)(g * H_ + k0 + col)) * I_ + kwi + (quad << 3);
        #pragma unroll
        for (int kk = 0; kk < 4; ++kk) Bx[g][kk] = ldb(bx + kk * 32);
    }

    const int hcol = k0 + col;
    const float bir = bi[hcol], biz = bi[H_ + hcol], bia = bi[2 * H_ + hcol], bnv = bn[hcol];

    for (int i = tid; i < 64 * 17; i += 256) h32s[i] = 0.f;
    __syncthreads();

    unsigned* myflag = flags + blockIdx.x * 16;
    const unsigned* grpflags = flags + (mt * 64) * 16;

    const f32x4 zero4 = {0.f, 0.f, 0.f, 0.f};

    for (int t = 0; t < S_; ++t) {
        f32x4 acc[4][4];   // [mi][0=r,1=z,2=ia,3=ha]
        #pragma unroll
        for (int mi = 0; mi < 4; ++mi)
            #pragma unroll
            for (int j = 0; j < 4; ++j) acc[mi][j] = zero4;

        // ---- x-phase (independent of h; overlaps group skew) ----
        const float* xbase = x + ((size_t)(b0 + col) * S_ + (size_t)t) * I_ + kwi + (quad << 3);
        #pragma unroll
        for (int kk = 0; kk < 4; ++kk) {
            #pragma unroll
            for (int mi = 0; mi < 4; ++mi) {
                const float* p = xbase + (size_t)mi * 16 * S_ * I_ + kk * 32;
                float4 f0 = *(const float4*)p;
                float4 f1 = *(const float4*)(p + 4);
                U16x8 u;
                u.u[0] = pack2bf(f0.x, f0.y);
                u.u[1] = pack2bf(f0.z, f0.w);
                u.u[2] = pack2bf(f1.x, f1.y);
                u.u[3] = pack2bf(f1.z, f1.w);
                bf16x8 a = u.b;
                acc[mi][0] = __builtin_amdgcn_mfma_f32_16x16x32_bf16(a, Bx[0][kk], acc[mi][0], 0, 0, 0);
                acc[mi][1] = __builtin_amdgcn_mfma_f32_16x16x32_bf16(a, Bx[1][kk], acc[mi][1], 0, 0, 0);
                acc[mi][2] = __builtin_amdgcn_mfma_f32_16x16x32_bf16(a, Bx[2][kk], acc[mi][2], 0, 0, 0);
            }
        }

        // ---- wait: all 64 blocks of this mt finished step t-1 ----
        if (t > 0) {
            if (w == 0) {
                const unsigned* fp = grpflags + lane * 16;   // lane i -> block i's flag
                while (__hip_atomic_load(fp, __ATOMIC_RELAXED, __HIP_MEMORY_SCOPE_AGENT) < (unsigned)t)
                    __builtin_amdgcn_s_sleep(1);
            }
            __syncthreads();
        }

        // ---- h-phase: device-scope loads bypass stale per-XCD L2 ----
        const unsigned short* hcur = (t & 1) ? hbufB : hbufA;
        const unsigned short* hrow = hcur + (size_t)(b0 + col) * H_ + kwh + (quad << 3);
        #pragma unroll
        for (int kk = 0; kk < 8; ++kk) {
            #pragma unroll
            for (int mi = 0; mi < 4; ++mi) {
                bf16x8 a = ldh_dev((const unsigned long long*)(hrow + (size_t)mi * 16 * H_ + kk * 32));
                acc[mi][0] = __builtin_amdgcn_mfma_f32_16x16x32_bf16(a, Bh[0][kk], acc[mi][0], 0, 0, 0);
                acc[mi][1] = __builtin_amdgcn_mfma_f32_16x16x32_bf16(a, Bh[1][kk], acc[mi][1], 0, 0, 0);
                acc[mi][3] = __builtin_amdgcn_mfma_f32_16x16x32_bf16(a, Bh[2][kk], acc[mi][3], 0, 0, 0);
            }
        }

        // ---- publish partials for the 3 m-slices this wave doesn't own ----
        #pragma unroll
        for (int mi = 0; mi < 4; ++mi) {
            if (mi == w) continue;
            int slot = mi - (mi > w ? 1 : 0);
            float* dst = partial + (size_t)((w * 3 + slot) * 16) * 68;
            #pragma unroll
            for (int j = 0; j < 4; ++j)
                #pragma unroll
                for (int r = 0; r < 4; ++r)
                    dst[((quad << 2) + r) * 68 + j * 16 + col] = acc[mi][j][r];
        }
        __syncthreads();

        // ---- epilogue: wave w handles batch rows [w*16, w*16+16) ----
        unsigned short* hnext = (t & 1) ? hbufA : hbufB;
        #pragma unroll
        for (int r = 0; r < 4; ++r) {
            float sr = 0.f, sz = 0.f, sia = 0.f, sha = 0.f;
            #pragma unroll
            for (int mi = 0; mi < 4; ++mi)
                if (mi == w) { sr = acc[mi][0][r]; sz = acc[mi][1][r]; sia = acc[mi][2][r]; sha = acc[mi][3][r]; }
            #pragma unroll
            for (int p = 0; p < 4; ++p) {
                if (p == w) continue;
                int slot = w - (w > p ? 1 : 0);
                const float* src = partial + (size_t)(((p * 3 + slot) * 16 + (quad << 2) + r)) * 68 + col;
                sr  += src[0];
                sz  += src[16];
                sia += src[32];
                sha += src[48];
            }
            float rg = 1.f / (1.f + __expf(-(sr + bir)));
            float zg = 1.f / (1.f + __expf(-(sz + biz)));
            float pa = sia + bia + rg * (sha + bnv);
            float e2 = __expf(2.f * pa);
            float ng = 1.f - 2.f / (e2 + 1.f);
            int m = (w << 4) + (quad << 2) + r;
            float hold = h32s[m * 17 + col];
            float hnew = ng + zg * (hold - ng);
            h32s[m * 17 + col] = hnew;
            size_t off = (size_t)(b0 + m) * H_ + k0 + col;
            // device-scope store: lands at coherence point, no fence needed
            __hip_atomic_store(hnext + off, f2bf1(hnew), __ATOMIC_RELAXED, __HIP_MEMORY_SCOPE_AGENT);
            if (t == S_ - 1) h32g[off] = hnew;
        }

        // ---- arrive: barrier drains vmcnt(0) (h stores acked at coherence
        //      point), then a single relaxed flag store ----
        __syncthreads();
        if (tid == 0)
            __hip_atomic_store(myflag, (unsigned)(t + 1), __ATOMIC_RELAXED, __HIP_MEMORY_SCOPE_AGENT);
    }
}

// -------- final linear: energies[b] = h_T[b] . wl + bl --------
__global__ __launch_bounds__(256) void final_kernel(const float* __restrict__ h32,
                                                    const float* __restrict__ wl,
                                                    const float* __restrict__ bl,
                                                    float* __restrict__ out) {
    const int b = blockIdx.x;
    float s = 0.f;
    for (int k = threadIdx.x; k < H_; k += 256)
        s += h32[((size_t)b << 10) + k] * wl[k];
    #pragma unroll
    for (int off = 32; off > 0; off >>= 1)
        s += __shfl_down(s, off, 64);
    __shared__ float red[4];
    const int wave = threadIdx.x >> 6;
    const int lane = threadIdx.x & 63;
    if (lane == 0) red[wave] = s;
    __syncthreads();
    if (threadIdx.x == 0)
        out[b] = red[0] + red[1] + red[2] + red[3] + bl[0];
}

extern "C" void kernel_launch(void* const* d_in, const int* in_sizes, int n_in,
                              void* d_out, int out_size, void* d_ws, size_t ws_size,
                              hipStream_t stream) {
    const float* x  = (const float*)d_in[0];
    const float* wi = (const float*)d_in[1];
    const float* wh = (const float*)d_in[2];
    const float* bi = (const float*)d_in[3];
    const float* bn = (const float*)d_in[4];
    const float* wl = (const float*)d_in[5];
    const float* bl = (const float*)d_in[6];
    float* out = (float*)d_out;

    // Workspace layout (~11 MB + 16 KB):
    // [0,1M)      h32g fp32 (256x1024)      [1M,1.5M)  hbA bf16
    // [1.5M,2M)   hbB bf16                  [2M,8M)    whb bf16 (3072x1024)
    // [8M,11M)    wib bf16 (3072x512)       [11M,+16K) flags (256 x 64B)
    char* ws = (char*)d_ws;
    float*          h32g  = (float*)ws;
    unsigned short* hbA   = (unsigned short*)(ws + (1u << 20));
    unsigned short* hbB   = (unsigned short*)(ws + (1u << 20) + (512u << 10));
    unsigned short* whb   = (unsigned short*)(ws + (2u << 20));
    unsigned short* wib   = (unsigned short*)(ws + (8u << 20));
    unsigned*       flags = (unsigned*)(ws + (11u << 20));

    prep_kernel<<<1024, 256, 0, stream>>>(wh, wi, (unsigned*)hbA, (unsigned*)whb, (unsigned*)wib, flags);
    gru_persistent<<<256, 256, 0, stream>>>(x, whb, wib, bi, bn, hbA, hbB, h32g, flags);
    final_kernel<<<B_, 256, 0, stream>>>(h32g, wl, bl, out);
}